// Round 6
// baseline (362.447 us; speedup 1.0000x reference)
//
#include <hip/hip_runtime.h>
#include <cstddef>

#define BB   8
#define TT   1024
#define DDIM 128
#define HH   8
#define DHH  16
#define FF   256
#define BT   (BB * TT)   // 8192

typedef unsigned short u16;
typedef __attribute__((ext_vector_type(8))) short short8;
typedef __attribute__((ext_vector_type(4))) float f32x4;

__device__ __forceinline__ u16 bf(float x) {
  unsigned u = __builtin_bit_cast(unsigned, x);
  u += 0x7fffu + ((u >> 16) & 1u);   // RTN-even
  return (u16)(u >> 16);
}
__device__ __forceinline__ u16 bft(float x) {           // truncate (P in [0,1])
  return (u16)(__builtin_bit_cast(unsigned, x) >> 16);
}

// fast gelu: x * sigmoid(1.59577x(1 + 0.044715x^2))
__device__ __forceinline__ float gelu_f(float x) {
  const float t = x * (0.79788456f + 0.03567740814f * x * x);
  return x / (1.0f + __expf(-2.0f * t));
}

// ---------------------------------------------------------------------------
// Weight prep: fp32 (K,N) -> bf16 (N,K)  (transpose + convert), 18 matrices.
// ---------------------------------------------------------------------------
struct PrepP { const float* W; u16* Wt; int K; int N; };
struct PrepArgs { PrepP p[18]; };

__global__ __launch_bounds__(256) void prep_k(PrepArgs a) {
  const PrepP pp = a.p[blockIdx.z];
  const int n0 = blockIdx.x * 64, k0 = blockIdx.y * 64;
  if (n0 >= pp.N || k0 >= pp.K) return;
  __shared__ float tile[64][65];
  const int tid = threadIdx.x;
  #pragma unroll
  for (int t = tid; t < 1024; t += 256) {
    const int kk = t >> 4, nn4 = (t & 15) << 2;
    float4 v = *(const float4*)(pp.W + (size_t)(k0 + kk) * pp.N + n0 + nn4);
    tile[nn4 + 0][kk] = v.x; tile[nn4 + 1][kk] = v.y;
    tile[nn4 + 2][kk] = v.z; tile[nn4 + 3][kk] = v.w;
  }
  __syncthreads();
  #pragma unroll
  for (int t = tid; t < 1024; t += 256) {
    const int nn = t >> 4, kk4 = (t & 15) << 2;
    ushort4 o;
    o.x = bf(tile[nn][kk4 + 0]); o.y = bf(tile[nn][kk4 + 1]);
    o.z = bf(tile[nn][kk4 + 2]); o.w = bf(tile[nn][kk4 + 3]);
    *(ushort4*)(pp.Wt + (size_t)(n0 + nn) * pp.K + k0 + kk4) = o;
  }
}

// ---------------------------------------------------------------------------
// Standalone LN (layer-0 LN1 only): fp32 in -> bf16 out. 4 rows / 256-thr block.
// ---------------------------------------------------------------------------
__global__ __launch_bounds__(256) void ln0_k(const float* __restrict__ X,
                                             const float* __restrict__ Y,
                                             const float* __restrict__ gx,
                                             const float* __restrict__ bx,
                                             const float* __restrict__ gy,
                                             const float* __restrict__ by,
                                             u16* __restrict__ ox,
                                             u16* __restrict__ oy) {
  const int which = blockIdx.y;
  const float* in = which ? Y : X;
  const float* g  = which ? gy : gx;
  const float* b  = which ? by : bx;
  u16* out        = which ? oy : ox;
  const int row  = blockIdx.x * 4 + (threadIdx.x >> 6);
  const int lane = threadIdx.x & 63;

  float2 v = *(const float2*)(in + (size_t)row * DDIM + lane * 2);
  float s  = v.x + v.y;
  float sq = v.x * v.x + v.y * v.y;
  #pragma unroll
  for (int off = 32; off >= 1; off >>= 1) {
    s  += __shfl_xor(s, off);
    sq += __shfl_xor(sq, off);
  }
  const float mean = s * (1.0f / DDIM);
  const float var  = sq * (1.0f / DDIM) - mean * mean;
  const float r    = rsqrtf(var + 1e-5f);
  float2 gg = *(const float2*)(g + lane * 2);
  float2 bb = *(const float2*)(b + lane * 2);
  ushort2 o;
  o.x = bf((v.x - mean) * r * gg.x + bb.x);
  o.y = bf((v.y - mean) * r * gg.y + bb.y);
  *(ushort2*)(out + (size_t)row * DDIM + lane * 2) = o;
}

// ---------------------------------------------------------------------------
// LDS-free bf16 MFMA GEMM: one 64-thread wave per block, 16 rows x 128 cols.
// A/B fragments loaded DIRECTLY from global (L1/L2-hot weights) — no LDS,
// no barriers. Fused epilogue: bias / gelu / +res / fp32 out / bf16 out /
// wave-local LayerNorm (requires N==128, gridDim.x==1).
// ---------------------------------------------------------------------------
struct GemmP { const u16* A; const u16* Wt; const float* bias; const float* res;
               float* outF; u16* outB; const float* g; const float* b; };
struct GemmArgs { GemmP p[6]; int K; int N; int gelu; int ln; };

__global__ __launch_bounds__(64) void gemml_k(GemmArgs a) {
  const GemmP pp = a.p[blockIdx.z];
  const int K = a.K, N = a.N;
  const int n0 = blockIdx.x * 128;
  const int m0 = blockIdx.y * 16;
  const int lane = threadIdx.x;
  const int l15 = lane & 15, quad = lane >> 4;

  f32x4 acc[8];
  #pragma unroll
  for (int j = 0; j < 8; ++j) acc[j] = {0.f, 0.f, 0.f, 0.f};

  const u16* Ap = pp.A  + (size_t)(m0 + l15) * K + quad * 8;
  const u16* Bp = pp.Wt + (size_t)(n0 + l15) * K + quad * 8;
  const size_t bstep = (size_t)16 * K;

  #pragma unroll 2
  for (int k = 0; k < K; k += 32) {
    const short8 av = *(const short8*)(Ap + k);
    #pragma unroll
    for (int j = 0; j < 8; ++j) {
      const short8 bv = *(const short8*)(Bp + (size_t)j * bstep + k);
      acc[j] = __builtin_amdgcn_mfma_f32_16x16x32_bf16(av, bv, acc[j], 0, 0, 0);
    }
  }

  // ---- epilogue: bias / gelu / res ----
  float vv[8][4];
  #pragma unroll
  for (int j = 0; j < 8; ++j) {
    const int n = n0 + j * 16 + l15;
    const float bias_v = pp.bias ? pp.bias[n] : 0.f;
    #pragma unroll
    for (int reg = 0; reg < 4; ++reg) {
      const int m = m0 + quad * 4 + reg;
      float v = acc[j][reg] + bias_v;
      if (a.gelu) v = gelu_f(v);
      if (pp.res) v += pp.res[(size_t)m * N + n];
      vv[j][reg] = v;
      if (pp.outF) pp.outF[(size_t)m * N + n] = v;
    }
  }

  if (!a.ln) {
    if (pp.outB) {
      #pragma unroll
      for (int j = 0; j < 8; ++j) {
        const int n = n0 + j * 16 + l15;
        #pragma unroll
        for (int reg = 0; reg < 4; ++reg)
          pp.outB[(size_t)(m0 + quad * 4 + reg) * N + n] = bf(vv[j][reg]);
      }
    }
    return;
  }

  // ---- wave-local LayerNorm (N==128: the wave holds full rows) ----
  #pragma unroll
  for (int reg = 0; reg < 4; ++reg) {
    float s = 0.f, q = 0.f;
    #pragma unroll
    for (int j = 0; j < 8; ++j) { const float v = vv[j][reg]; s += v; q += v * v; }
    #pragma unroll
    for (int off = 8; off >= 1; off >>= 1) {
      s += __shfl_xor(s, off, 16);
      q += __shfl_xor(q, off, 16);
    }
    const float mean = s * (1.0f / 128.f);
    const float var  = q * (1.0f / 128.f) - mean * mean;
    const float r    = rsqrtf(var + 1e-5f);
    const int m = m0 + quad * 4 + reg;
    #pragma unroll
    for (int j = 0; j < 8; ++j) {
      const int n = j * 16 + l15;
      pp.outB[(size_t)m * 128 + n] = bf((vv[j][reg] - mean) * r * pp.g[n] + pp.b[n]);
    }
  }
}

// ---------------------------------------------------------------------------
// MFMA flash attention (shared softmax). 64 q-rows / block (wave owns 16).
// Q and K fragments loaded directly from global (no K staging); V transposed
// via double-buffered LDS (one barrier per key tile); P via wave-private LDS.
// ---------------------------------------------------------------------------
__global__ __launch_bounds__(256) void attn_k(const u16* __restrict__ qx,
                                              const u16* __restrict__ kx,
                                              const u16* __restrict__ vx,
                                              const u16* __restrict__ qy,
                                              const u16* __restrict__ ky,
                                              const u16* __restrict__ vy,
                                              u16* __restrict__ o1,
                                              u16* __restrict__ o2) {
  const int t0 = blockIdx.x * 64;
  const int bh = blockIdx.y;
  const int b = bh >> 3, h = bh & 7;
  const size_t base = (size_t)b * TT * DDIM + h * DHH;

  __shared__ __align__(16) u16 Vt[2][32][72];  // [buf][c][s0..63]
  __shared__ __align__(16) u16 Ps[64][72];     // [q][s0..63] (wave-private rows)

  const int tid  = threadIdx.x;
  const int w    = tid >> 6;
  const int lane = tid & 63;
  const int l15  = lane & 15;
  const int quad = lane >> 4;

  // Q A-fragment: row m = l15, k = quad*8+j
  const u16* qp = (quad < 2) ? qx : qy;
  const u16* kp = (quad < 2) ? kx : ky;
  const int dq = (quad & 1) * 8;
  const short8 qa = *(const short8*)(qp + base + (size_t)(t0 + w * 16 + l15) * DDIM + dq);
  const u16* kfrag = kp + base + (size_t)l15 * DDIM + dq;   // + s0*DDIM per tile

  f32x4 Of0 = {0.f, 0.f, 0.f, 0.f};
  f32x4 Of1 = {0.f, 0.f, 0.f, 0.f};
  float l_i[4] = {0.f, 0.f, 0.f, 0.f};

  #define STAGE_V(kt, buf)                                                        \
    do {                                                                          \
      const int s0_ = (kt) * 64;                                                  \
      _Pragma("unroll")                                                           \
      for (int t = tid; t < 512; t += 256) {                                      \
        const int c = t & 31;                                                     \
        const int sb = (t >> 5) << 2;                                             \
        const u16* vp = (c < 16) ? vx : vy;                                       \
        const int cc = c & 15;                                                    \
        const size_t ro = base + (size_t)(s0_ + sb) * DDIM + cc;                  \
        ushort4 w4;                                                               \
        w4.x = vp[ro];                                                            \
        w4.y = vp[ro + DDIM];                                                     \
        w4.z = vp[ro + 2 * DDIM];                                                 \
        w4.w = vp[ro + 3 * DDIM];                                                 \
        *(ushort4*)&Vt[buf][c][sb] = w4;                                          \
      }                                                                           \
    } while (0)

  STAGE_V(0, 0);

  for (int kt = 0; kt < TT / 64; ++kt) {
    const int buf = kt & 1;

    // K fragments for this tile: direct global loads (L1/L2-hot), issued
    // before the barrier so the latency overlaps with it.
    short8 kb[4];
    #pragma unroll
    for (int t = 0; t < 4; ++t)
      kb[t] = *(const short8*)(kfrag + (size_t)(kt * 64 + t * 16) * DDIM);

    __syncthreads();
    if (kt + 1 < TT / 64) STAGE_V(kt + 1, buf ^ 1);

    // S = Q'.K'^T : 4 MFMAs
    f32x4 Sf[4];
    #pragma unroll
    for (int t = 0; t < 4; ++t) {
      f32x4 z = {0.f, 0.f, 0.f, 0.f};
      Sf[t] = __builtin_amdgcn_mfma_f32_16x16x32_bf16(qa, kb[t], z, 0, 0, 0);
    }

    // p = exp2(S * 0.125*log2e); lane-local denominators; truncate-pack to LDS
    #pragma unroll
    for (int reg = 0; reg < 4; ++reg) {
      const float p0 = exp2f(Sf[0][reg] * 0.18033688011112042f);
      const float p1 = exp2f(Sf[1][reg] * 0.18033688011112042f);
      const float p2 = exp2f(Sf[2][reg] * 0.18033688011112042f);
      const float p3 = exp2f(Sf[3][reg] * 0.18033688011112042f);
      l_i[reg] += p0 + p1 + p2 + p3;
      const int q = w * 16 + quad * 4 + reg;
      Ps[q][l15]      = bft(p0);
      Ps[q][16 + l15] = bft(p1);
      Ps[q][32 + l15] = bft(p2);
      Ps[q][48 + l15] = bft(p3);
    }

    // O += P @ V'   (wave-private Ps rows: no barrier needed)
    #pragma unroll
    for (int sh = 0; sh < 2; ++sh) {
      short8 pa  = *(const short8*)&Ps[w * 16 + l15][sh * 32 + quad * 8];
      short8 vb0 = *(const short8*)&Vt[buf][l15][sh * 32 + quad * 8];
      short8 vb1 = *(const short8*)&Vt[buf][16 + l15][sh * 32 + quad * 8];
      Of0 = __builtin_amdgcn_mfma_f32_16x16x32_bf16(pa, vb0, Of0, 0, 0, 0);
      Of1 = __builtin_amdgcn_mfma_f32_16x16x32_bf16(pa, vb1, Of1, 0, 0, 0);
    }
  }
  #undef STAGE_V

  // epilogue: reduce denominators (16 lanes/row), normalize, write bf16
  #pragma unroll
  for (int reg = 0; reg < 4; ++reg) {
    float l = l_i[reg];
    #pragma unroll
    for (int off = 8; off >= 1; off >>= 1) l += __shfl_xor(l, off, 16);
    const float inv = 1.0f / l;
    const size_t r = base + (size_t)(t0 + w * 16 + quad * 4 + reg) * DDIM + l15;
    o1[r] = bf(Of0[reg] * inv);
    o2[r] = bf(Of1[reg] * inv);
  }
}

// ---------------------------------------------------------------------------
extern "C" void kernel_launch(void* const* d_in, const int* in_sizes, int n_in,
                              void* d_out, int out_size, void* d_ws, size_t ws_size,
                              hipStream_t stream) {
  const float* x_in  = (const float*)d_in[0];
  const float* y_in  = (const float*)d_in[1];
  const float* Wq    = (const float*)d_in[2];
  const float* Wk    = (const float*)d_in[3];
  const float* Wv    = (const float*)d_in[4];
  const float* Wox   = (const float*)d_in[5];
  const float* box   = (const float*)d_in[6];
  const float* Woy   = (const float*)d_in[7];
  const float* boy   = (const float*)d_in[8];
  const float* ln1xg = (const float*)d_in[9];
  const float* ln1xb = (const float*)d_in[10];
  const float* ln1yg = (const float*)d_in[11];
  const float* ln1yb = (const float*)d_in[12];
  const float* ln2xg = (const float*)d_in[13];
  const float* ln2xb = (const float*)d_in[14];
  const float* ln2yg = (const float*)d_in[15];
  const float* ln2yb = (const float*)d_in[16];
  const float* fxw1  = (const float*)d_in[17];
  const float* fxb1  = (const float*)d_in[18];
  const float* fxw2  = (const float*)d_in[19];
  const float* fxb2  = (const float*)d_in[20];
  const float* fyw1  = (const float*)d_in[21];
  const float* fyb1  = (const float*)d_in[22];
  const float* fyw2  = (const float*)d_in[23];
  const float* fyb2  = (const float*)d_in[24];

  const size_t S = (size_t)BT * DDIM;  // 1,048,576 elems
  float* X = (float*)d_out;
  float* Y = X + S;

  char* wsb = (char*)d_ws;
  auto carve = [&](size_t bytes) { char* p = wsb; wsb += (bytes + 255) & ~(size_t)255; return p; };
  u16* xn  = (u16*)carve(S * 2);
  u16* yn  = (u16*)carve(S * 2);
  u16* qx  = (u16*)carve(S * 2);
  u16* kx  = (u16*)carve(S * 2);
  u16* vx  = (u16*)carve(S * 2);
  u16* qy  = (u16*)carve(S * 2);
  u16* ky  = (u16*)carve(S * 2);
  u16* vy  = (u16*)carve(S * 2);
  u16* ob1 = (u16*)carve(S * 2);
  u16* ob2 = (u16*)carve(S * 2);
  u16* hx  = (u16*)carve(2 * S * 2);
  u16* hy  = (u16*)carve(2 * S * 2);
  u16* WqT[2], *WkT[2], *WvT[2], *WoxT[2], *WoyT[2];
  u16* f1xT[2], *f1yT[2], *f2xT[2], *f2yT[2];
  for (int l = 0; l < 2; ++l) {
    WqT[l]  = (u16*)carve(16384 * 2);
    WkT[l]  = (u16*)carve(16384 * 2);
    WvT[l]  = (u16*)carve(16384 * 2);
    WoxT[l] = (u16*)carve(16384 * 2);
    WoyT[l] = (u16*)carve(16384 * 2);
    f1xT[l] = (u16*)carve(32768 * 2);
    f1yT[l] = (u16*)carve(32768 * 2);
    f2xT[l] = (u16*)carve(32768 * 2);
    f2yT[l] = (u16*)carve(32768 * 2);
  }

  // weight transpose+convert (all layers, one kernel)
  {
    PrepArgs a;
    int idx = 0;
    for (int l = 0; l < 2; ++l) {
      a.p[idx++] = {Wq  + (size_t)l * 16384, WqT[l],  128, 128};
      a.p[idx++] = {Wk  + (size_t)l * 16384, WkT[l],  128, 128};
      a.p[idx++] = {Wv  + (size_t)l * 16384, WvT[l],  128, 128};
      a.p[idx++] = {Wox + (size_t)l * 16384, WoxT[l], 128, 128};
      a.p[idx++] = {Woy + (size_t)l * 16384, WoyT[l], 128, 128};
      a.p[idx++] = {fxw1 + (size_t)l * 32768, f1xT[l], 128, 256};
      a.p[idx++] = {fyw1 + (size_t)l * 32768, f1yT[l], 128, 256};
      a.p[idx++] = {fxw2 + (size_t)l * 32768, f2xT[l], 256, 128};
      a.p[idx++] = {fyw2 + (size_t)l * 32768, f2yT[l], 256, 128};
    }
    prep_k<<<dim3(4, 4, 18), 256, 0, stream>>>(a);
  }

  // layer-0 LN1 (only standalone LN)
  ln0_k<<<dim3(BT / 4, 2), 256, 0, stream>>>(x_in, y_in, ln1xg, ln1xb, ln1yg, ln1yb, xn, yn);

  for (int l = 0; l < 2; ++l) {
    const size_t bo  = (size_t)l * DDIM;
    const size_t fbo = (size_t)l * FF;

    // QKV (6-way batched): pure bf16 out
    {
      GemmArgs a = {}; a.K = DDIM; a.N = DDIM; a.gelu = 0; a.ln = 0;
      a.p[0] = {yn, WqT[l], nullptr, nullptr, nullptr, qx, nullptr, nullptr};
      a.p[1] = {xn, WkT[l], nullptr, nullptr, nullptr, kx, nullptr, nullptr};
      a.p[2] = {xn, WvT[l], nullptr, nullptr, nullptr, vx, nullptr, nullptr};
      a.p[3] = {xn, WqT[l], nullptr, nullptr, nullptr, qy, nullptr, nullptr};
      a.p[4] = {yn, WkT[l], nullptr, nullptr, nullptr, ky, nullptr, nullptr};
      a.p[5] = {yn, WvT[l], nullptr, nullptr, nullptr, vy, nullptr, nullptr};
      gemml_k<<<dim3(1, BT / 16, 6), 64, 0, stream>>>(a);
    }
    // fused attention
    attn_k<<<dim3(TT / 64, BB * HH), 256, 0, stream>>>(qx, kx, vx, qy, ky, vy, ob1, ob2);
    // output proj + residual + LN2 -> X (fp32) and xn (bf16)
    {
      const float* resx = (l == 0) ? x_in : X;
      const float* resy = (l == 0) ? y_in : Y;
      GemmArgs a = {}; a.K = DDIM; a.N = DDIM; a.gelu = 0; a.ln = 1;
      a.p[0] = {ob1, WoxT[l], box + bo, resx, X, xn, ln2xg + bo, ln2xb + bo};
      a.p[1] = {ob2, WoyT[l], boy + bo, resy, Y, yn, ln2yg + bo, ln2yb + bo};
      gemml_k<<<dim3(1, BT / 16, 2), 64, 0, stream>>>(a);
    }
    // FFN1 + gelu (bf16 out)
    {
      GemmArgs a = {}; a.K = DDIM; a.N = FF; a.gelu = 1; a.ln = 0;
      a.p[0] = {xn, f1xT[l], fxb1 + fbo, nullptr, nullptr, hx, nullptr, nullptr};
      a.p[1] = {yn, f1yT[l], fyb1 + fbo, nullptr, nullptr, hy, nullptr, nullptr};
      gemml_k<<<dim3(2, BT / 16, 2), 64, 0, stream>>>(a);
    }
    // FFN2 + residual -> X; layer 0 also fuses next layer's LN1 -> xn
    {
      GemmArgs a = {}; a.K = FF; a.N = DDIM; a.gelu = 0; a.ln = (l == 0) ? 1 : 0;
      if (l == 0) {
        a.p[0] = {hx, f2xT[l], fxb2 + bo, X, X, xn, ln1xg + DDIM, ln1xb + DDIM};
        a.p[1] = {hy, f2yT[l], fyb2 + bo, Y, Y, yn, ln1yg + DDIM, ln1yb + DDIM};
      } else {
        a.p[0] = {hx, f2xT[l], fxb2 + bo, X, X, nullptr, nullptr, nullptr};
        a.p[1] = {hy, f2yT[l], fyb2 + bo, Y, Y, nullptr, nullptr, nullptr};
      }
      gemml_k<<<dim3(1, BT / 16, 2), 64, 0, stream>>>(a);
    }
  }
}

// Round 7
// 279.143 us; speedup vs baseline: 1.2984x; 1.2984x over previous
//
#include <hip/hip_runtime.h>
#include <cstddef>

#define BB   8
#define TT   1024
#define DDIM 128
#define HH   8
#define DHH  16
#define FF   256
#define BT   (BB * TT)   // 8192

typedef unsigned short u16;
typedef __attribute__((ext_vector_type(8))) short short8;
typedef __attribute__((ext_vector_type(4))) float f32x4;

__device__ __forceinline__ u16 bf(float x) {
  unsigned u = __builtin_bit_cast(unsigned, x);
  u += 0x7fffu + ((u >> 16) & 1u);   // RTN-even
  return (u16)(u >> 16);
}
__device__ __forceinline__ u16 bft(float x) {           // truncate (P in [0,1])
  return (u16)(__builtin_bit_cast(unsigned, x) >> 16);
}

// fast gelu: x * sigmoid(1.59577x(1 + 0.044715x^2))
__device__ __forceinline__ float gelu_f(float x) {
  const float t = x * (0.79788456f + 0.03567740814f * x * x);
  return x / (1.0f + __expf(-2.0f * t));
}

// ---------------------------------------------------------------------------
// Weight prep: fp32 (K,N) -> bf16 (N,K)  (transpose + convert), 18 matrices.
// ---------------------------------------------------------------------------
struct PrepP { const float* W; u16* Wt; int K; int N; };
struct PrepArgs { PrepP p[18]; };

__global__ __launch_bounds__(256) void prep_k(PrepArgs a) {
  const PrepP pp = a.p[blockIdx.z];
  const int n0 = blockIdx.x * 64, k0 = blockIdx.y * 64;
  if (n0 >= pp.N || k0 >= pp.K) return;
  __shared__ float tile[64][65];
  const int tid = threadIdx.x;
  #pragma unroll
  for (int t = tid; t < 1024; t += 256) {
    const int kk = t >> 4, nn4 = (t & 15) << 2;
    float4 v = *(const float4*)(pp.W + (size_t)(k0 + kk) * pp.N + n0 + nn4);
    tile[nn4 + 0][kk] = v.x; tile[nn4 + 1][kk] = v.y;
    tile[nn4 + 2][kk] = v.z; tile[nn4 + 3][kk] = v.w;
  }
  __syncthreads();
  #pragma unroll
  for (int t = tid; t < 1024; t += 256) {
    const int nn = t >> 4, kk4 = (t & 15) << 2;
    ushort4 o;
    o.x = bf(tile[nn][kk4 + 0]); o.y = bf(tile[nn][kk4 + 1]);
    o.z = bf(tile[nn][kk4 + 2]); o.w = bf(tile[nn][kk4 + 3]);
    *(ushort4*)(pp.Wt + (size_t)(n0 + nn) * pp.K + k0 + kk4) = o;
  }
}

// ---------------------------------------------------------------------------
// Standalone LN (layer-0 LN1 only): fp32 in -> bf16 out. 4 rows / 256-thr block.
// ---------------------------------------------------------------------------
__global__ __launch_bounds__(256) void ln0_k(const float* __restrict__ X,
                                             const float* __restrict__ Y,
                                             const float* __restrict__ gx,
                                             const float* __restrict__ bx,
                                             const float* __restrict__ gy,
                                             const float* __restrict__ by,
                                             u16* __restrict__ ox,
                                             u16* __restrict__ oy) {
  const int which = blockIdx.y;
  const float* in = which ? Y : X;
  const float* g  = which ? gy : gx;
  const float* b  = which ? by : bx;
  u16* out        = which ? oy : ox;
  const int row  = blockIdx.x * 4 + (threadIdx.x >> 6);
  const int lane = threadIdx.x & 63;

  float2 v = *(const float2*)(in + (size_t)row * DDIM + lane * 2);
  float s  = v.x + v.y;
  float sq = v.x * v.x + v.y * v.y;
  #pragma unroll
  for (int off = 32; off >= 1; off >>= 1) {
    s  += __shfl_xor(s, off);
    sq += __shfl_xor(sq, off);
  }
  const float mean = s * (1.0f / DDIM);
  const float var  = sq * (1.0f / DDIM) - mean * mean;
  const float r    = rsqrtf(var + 1e-5f);
  float2 gg = *(const float2*)(g + lane * 2);
  float2 bb = *(const float2*)(b + lane * 2);
  ushort2 o;
  o.x = bf((v.x - mean) * r * gg.x + bb.x);
  o.y = bf((v.y - mean) * r * gg.y + bb.y);
  *(ushort2*)(out + (size_t)row * DDIM + lane * 2) = o;
}

// ---------------------------------------------------------------------------
// bf16 MFMA GEMM, 32x128 tile, 256 threads = 4 waves (wr = row-half of 16,
// wc = col-half of 64). BK=128: K=128 ops run single-stage (ONE barrier);
// K=256 runs two stages. Padded LDS rows (136 u16) -> 2-way (free) reads.
// Fused epilogue: bias / gelu / +res fp32 / bf16 out / per-row LayerNorm
// (ln requires N==128, gridDim.x==1).
// ---------------------------------------------------------------------------
struct GemmP { const u16* A; const u16* Wt; const float* bias; const float* res;
               float* outF; u16* outB; const float* g; const float* b; };
struct GemmArgs { GemmP p[6]; int K; int N; int gelu; int ln; };

__global__ __launch_bounds__(256) void gemmf_k(GemmArgs a) {
  const GemmP pp = a.p[blockIdx.z];
  const int K = a.K, N = a.N;
  const int n0 = blockIdx.x * 128, m0 = blockIdx.y * 32;
  __shared__ __align__(16) u16 As[32][136];
  __shared__ __align__(16) u16 Bs[128][136];
  __shared__ float2 stats[32][2];
  const int tid  = threadIdx.x;
  const int w    = tid >> 6;
  const int lane = tid & 63;
  const int l15  = lane & 15;
  const int quad = lane >> 4;
  const int wr = w & 1, wc = w >> 1;

  f32x4 acc[4];
  #pragma unroll
  for (int j = 0; j < 4; ++j) acc[j] = {0.f, 0.f, 0.f, 0.f};

  for (int k0 = 0; k0 < K; k0 += 128) {
    #pragma unroll
    for (int t = tid; t < 512; t += 256) {
      const int r = t >> 4, g = (t & 15) << 3;
      *(short8*)&As[r][g] = *(const short8*)(pp.A + (size_t)(m0 + r) * K + k0 + g);
    }
    #pragma unroll
    for (int t = tid; t < 2048; t += 256) {
      const int r = t >> 4, g = (t & 15) << 3;
      *(short8*)&Bs[r][g] = *(const short8*)(pp.Wt + (size_t)(n0 + r) * K + k0 + g);
    }
    __syncthreads();
    #pragma unroll
    for (int ks = 0; ks < 4; ++ks) {
      const short8 ar = *(const short8*)&As[wr * 16 + l15][ks * 32 + quad * 8];
      #pragma unroll
      for (int j = 0; j < 4; ++j) {
        const short8 br = *(const short8*)&Bs[wc * 64 + j * 16 + l15][ks * 32 + quad * 8];
        acc[j] = __builtin_amdgcn_mfma_f32_16x16x32_bf16(ar, br, acc[j], 0, 0, 0);
      }
    }
    if (k0 + 128 < K) __syncthreads();
  }

  // ---- epilogue: bias / gelu / res, raw fp32 store ----
  #pragma unroll
  for (int j = 0; j < 4; ++j) {
    const int n = n0 + wc * 64 + j * 16 + l15;
    const float bias_v = pp.bias ? pp.bias[n] : 0.f;
    #pragma unroll
    for (int reg = 0; reg < 4; ++reg) {
      const int m = m0 + wr * 16 + quad * 4 + reg;
      float v = acc[j][reg] + bias_v;
      if (a.gelu) v = gelu_f(v);
      if (pp.res) v += pp.res[(size_t)m * N + n];
      acc[j][reg] = v;
      if (pp.outF) pp.outF[(size_t)m * N + n] = v;
    }
  }

  if (!a.ln) {
    if (pp.outB) {
      #pragma unroll
      for (int j = 0; j < 4; ++j) {
        const int n = n0 + wc * 64 + j * 16 + l15;
        #pragma unroll
        for (int reg = 0; reg < 4; ++reg) {
          const int m = m0 + wr * 16 + quad * 4 + reg;
          pp.outB[(size_t)m * N + n] = bf(acc[j][reg]);
        }
      }
    }
    return;
  }

  // ---- fused LayerNorm (N==128: both col-halves in this block) ----
  #pragma unroll
  for (int reg = 0; reg < 4; ++reg) {
    float s = 0.f, q = 0.f;
    #pragma unroll
    for (int j = 0; j < 4; ++j) { const float v = acc[j][reg]; s += v; q += v * v; }
    #pragma unroll
    for (int off = 8; off >= 1; off >>= 1) {
      s += __shfl_xor(s, off, 16);
      q += __shfl_xor(q, off, 16);
    }
    if (l15 == 0) stats[wr * 16 + quad * 4 + reg][wc] = make_float2(s, q);
  }
  __syncthreads();
  #pragma unroll
  for (int reg = 0; reg < 4; ++reg) {
    const int mloc = wr * 16 + quad * 4 + reg;
    const float2 s0 = stats[mloc][0], s1 = stats[mloc][1];
    const float mean = (s0.x + s1.x) * (1.0f / 128.f);
    const float var  = (s0.y + s1.y) * (1.0f / 128.f) - mean * mean;
    const float r    = rsqrtf(var + 1e-5f);
    #pragma unroll
    for (int j = 0; j < 4; ++j) {
      const int n = wc * 64 + j * 16 + l15;
      pp.outB[(size_t)(m0 + mloc) * 128 + n] =
          bf((acc[j][reg] - mean) * r * pp.g[n] + pp.b[n]);
    }
  }
}

// ---------------------------------------------------------------------------
// MFMA flash attention (shared softmax). 64 q-rows / block (wave owns 16),
// double-buffered K/V staging, one barrier per key tile. V staged via
// coalesced short8 row loads + ds_write_b16 transpose.
// ---------------------------------------------------------------------------
__global__ __launch_bounds__(256) void attn_k(const u16* __restrict__ qx,
                                              const u16* __restrict__ kx,
                                              const u16* __restrict__ vx,
                                              const u16* __restrict__ qy,
                                              const u16* __restrict__ ky,
                                              const u16* __restrict__ vy,
                                              u16* __restrict__ o1,
                                              u16* __restrict__ o2) {
  const int t0 = blockIdx.x * 64;
  const int bh = blockIdx.y;
  const int b = bh >> 3, h = bh & 7;
  const size_t base = (size_t)b * TT * DDIM + h * DHH;

  __shared__ __align__(16) u16 Ks[2][64][40];  // [buf][s][d0..31]
  __shared__ __align__(16) u16 Vt[2][32][72];  // [buf][c][s0..63]
  __shared__ __align__(16) u16 Ps[64][72];     // [q][s0..63] (wave-private rows)

  const int tid  = threadIdx.x;
  const int w    = tid >> 6;
  const int lane = tid & 63;
  const int l15  = lane & 15;
  const int quad = lane >> 4;

  // Q A-fragment: row m = l15, k = quad*8+j
  const u16* qp = (quad < 2) ? qx : qy;
  const int dq = (quad & 1) * 8;
  const short8 qa = *(const short8*)(qp + base + (size_t)(t0 + w * 16 + l15) * DDIM + dq);

  f32x4 Of0 = {0.f, 0.f, 0.f, 0.f};
  f32x4 Of1 = {0.f, 0.f, 0.f, 0.f};
  float l_i[4] = {0.f, 0.f, 0.f, 0.f};

  // K staging params (uniform per thread): one 16B chunk per thread
  const int ks_s = tid >> 2, ks_c = tid & 3;
  const u16* ks_p = (ks_c < 2) ? kx : ky;
  const int ks_d8 = (ks_c & 1) * 8;
  const int ks_col = (ks_c < 2 ? 0 : 16) + ks_d8;

  // V staging params: wave w owns col-group w; lane = s-row
  const u16* vs_p = (w < 2) ? vx : vy;
  const int vs_cc = (w & 1) * 8;                 // source col offset within head
  const int vs_cb = (w < 2 ? 0 : 16) + vs_cc;    // dest col base in Vt

  #define STAGE(kt, buf)                                                          \
    do {                                                                          \
      const int s0_ = (kt) * 64;                                                  \
      *(short8*)&Ks[buf][ks_s][ks_col] =                                          \
          *(const short8*)(ks_p + base + (size_t)(s0_ + ks_s) * DDIM + ks_d8);    \
      const short8 v8 =                                                           \
          *(const short8*)(vs_p + base + (size_t)(s0_ + lane) * DDIM + vs_cc);    \
      _Pragma("unroll")                                                           \
      for (int e = 0; e < 8; ++e) Vt[buf][vs_cb + e][lane] = (u16)v8[e];          \
    } while (0)

  STAGE(0, 0);

  for (int kt = 0; kt < TT / 64; ++kt) {
    const int buf = kt & 1;
    __syncthreads();
    if (kt + 1 < TT / 64) STAGE(kt + 1, buf ^ 1);

    // S = Q'.K'^T : 4 MFMAs
    f32x4 Sf[4];
    #pragma unroll
    for (int t = 0; t < 4; ++t) {
      short8 kb = *(const short8*)&Ks[buf][t * 16 + l15][quad * 8];
      f32x4 z = {0.f, 0.f, 0.f, 0.f};
      Sf[t] = __builtin_amdgcn_mfma_f32_16x16x32_bf16(qa, kb, z, 0, 0, 0);
    }

    // p = exp2(S * 0.125*log2e); lane-local denominators; truncate-pack to LDS
    #pragma unroll
    for (int reg = 0; reg < 4; ++reg) {
      const float p0 = exp2f(Sf[0][reg] * 0.18033688011112042f);
      const float p1 = exp2f(Sf[1][reg] * 0.18033688011112042f);
      const float p2 = exp2f(Sf[2][reg] * 0.18033688011112042f);
      const float p3 = exp2f(Sf[3][reg] * 0.18033688011112042f);
      l_i[reg] += p0 + p1 + p2 + p3;
      const int q = w * 16 + quad * 4 + reg;
      Ps[q][l15]      = bft(p0);
      Ps[q][16 + l15] = bft(p1);
      Ps[q][32 + l15] = bft(p2);
      Ps[q][48 + l15] = bft(p3);
    }

    // O += P @ V'   (wave-private Ps rows: no barrier needed)
    #pragma unroll
    for (int sh = 0; sh < 2; ++sh) {
      short8 pa  = *(const short8*)&Ps[w * 16 + l15][sh * 32 + quad * 8];
      short8 vb0 = *(const short8*)&Vt[buf][l15][sh * 32 + quad * 8];
      short8 vb1 = *(const short8*)&Vt[buf][16 + l15][sh * 32 + quad * 8];
      Of0 = __builtin_amdgcn_mfma_f32_16x16x32_bf16(pa, vb0, Of0, 0, 0, 0);
      Of1 = __builtin_amdgcn_mfma_f32_16x16x32_bf16(pa, vb1, Of1, 0, 0, 0);
    }
  }
  #undef STAGE

  // epilogue: reduce denominators (16 lanes/row), normalize, write bf16
  #pragma unroll
  for (int reg = 0; reg < 4; ++reg) {
    float l = l_i[reg];
    #pragma unroll
    for (int off = 8; off >= 1; off >>= 1) l += __shfl_xor(l, off, 16);
    const float inv = 1.0f / l;
    const size_t r = base + (size_t)(t0 + w * 16 + quad * 4 + reg) * DDIM + l15;
    o1[r] = bf(Of0[reg] * inv);
    o2[r] = bf(Of1[reg] * inv);
  }
}

// ---------------------------------------------------------------------------
extern "C" void kernel_launch(void* const* d_in, const int* in_sizes, int n_in,
                              void* d_out, int out_size, void* d_ws, size_t ws_size,
                              hipStream_t stream) {
  const float* x_in  = (const float*)d_in[0];
  const float* y_in  = (const float*)d_in[1];
  const float* Wq    = (const float*)d_in[2];
  const float* Wk    = (const float*)d_in[3];
  const float* Wv    = (const float*)d_in[4];
  const float* Wox   = (const float*)d_in[5];
  const float* box   = (const float*)d_in[6];
  const float* Woy   = (const float*)d_in[7];
  const float* boy   = (const float*)d_in[8];
  const float* ln1xg = (const float*)d_in[9];
  const float* ln1xb = (const float*)d_in[10];
  const float* ln1yg = (const float*)d_in[11];
  const float* ln1yb = (const float*)d_in[12];
  const float* ln2xg = (const float*)d_in[13];
  const float* ln2xb = (const float*)d_in[14];
  const float* ln2yg = (const float*)d_in[15];
  const float* ln2yb = (const float*)d_in[16];
  const float* fxw1  = (const float*)d_in[17];
  const float* fxb1  = (const float*)d_in[18];
  const float* fxw2  = (const float*)d_in[19];
  const float* fxb2  = (const float*)d_in[20];
  const float* fyw1  = (const float*)d_in[21];
  const float* fyb1  = (const float*)d_in[22];
  const float* fyw2  = (const float*)d_in[23];
  const float* fyb2  = (const float*)d_in[24];

  const size_t S = (size_t)BT * DDIM;  // 1,048,576 elems
  float* X = (float*)d_out;
  float* Y = X + S;

  char* wsb = (char*)d_ws;
  auto carve = [&](size_t bytes) { char* p = wsb; wsb += (bytes + 255) & ~(size_t)255; return p; };
  u16* xn  = (u16*)carve(S * 2);
  u16* yn  = (u16*)carve(S * 2);
  u16* qx  = (u16*)carve(S * 2);
  u16* kx  = (u16*)carve(S * 2);
  u16* vx  = (u16*)carve(S * 2);
  u16* qy  = (u16*)carve(S * 2);
  u16* ky  = (u16*)carve(S * 2);
  u16* vy  = (u16*)carve(S * 2);
  u16* ob1 = (u16*)carve(S * 2);
  u16* ob2 = (u16*)carve(S * 2);
  u16* hx  = (u16*)carve(2 * S * 2);
  u16* hy  = (u16*)carve(2 * S * 2);
  u16* WqT[2], *WkT[2], *WvT[2], *WoxT[2], *WoyT[2];
  u16* f1xT[2], *f1yT[2], *f2xT[2], *f2yT[2];
  for (int l = 0; l < 2; ++l) {
    WqT[l]  = (u16*)carve(16384 * 2);
    WkT[l]  = (u16*)carve(16384 * 2);
    WvT[l]  = (u16*)carve(16384 * 2);
    WoxT[l] = (u16*)carve(16384 * 2);
    WoyT[l] = (u16*)carve(16384 * 2);
    f1xT[l] = (u16*)carve(32768 * 2);
    f1yT[l] = (u16*)carve(32768 * 2);
    f2xT[l] = (u16*)carve(32768 * 2);
    f2yT[l] = (u16*)carve(32768 * 2);
  }

  // weight transpose+convert (all layers, one kernel)
  {
    PrepArgs a;
    int idx = 0;
    for (int l = 0; l < 2; ++l) {
      a.p[idx++] = {Wq  + (size_t)l * 16384, WqT[l],  128, 128};
      a.p[idx++] = {Wk  + (size_t)l * 16384, WkT[l],  128, 128};
      a.p[idx++] = {Wv  + (size_t)l * 16384, WvT[l],  128, 128};
      a.p[idx++] = {Wox + (size_t)l * 16384, WoxT[l], 128, 128};
      a.p[idx++] = {Woy + (size_t)l * 16384, WoyT[l], 128, 128};
      a.p[idx++] = {fxw1 + (size_t)l * 32768, f1xT[l], 128, 256};
      a.p[idx++] = {fyw1 + (size_t)l * 32768, f1yT[l], 128, 256};
      a.p[idx++] = {fxw2 + (size_t)l * 32768, f2xT[l], 256, 128};
      a.p[idx++] = {fyw2 + (size_t)l * 32768, f2yT[l], 256, 128};
    }
    prep_k<<<dim3(4, 4, 18), 256, 0, stream>>>(a);
  }

  // layer-0 LN1 (only standalone LN)
  ln0_k<<<dim3(BT / 4, 2), 256, 0, stream>>>(x_in, y_in, ln1xg, ln1xb, ln1yg, ln1yb, xn, yn);

  for (int l = 0; l < 2; ++l) {
    const size_t bo  = (size_t)l * DDIM;
    const size_t fbo = (size_t)l * FF;

    // QKV (6-way batched): pure bf16 out
    {
      GemmArgs a = {}; a.K = DDIM; a.N = DDIM; a.gelu = 0; a.ln = 0;
      a.p[0] = {yn, WqT[l], nullptr, nullptr, nullptr, qx, nullptr, nullptr};
      a.p[1] = {xn, WkT[l], nullptr, nullptr, nullptr, kx, nullptr, nullptr};
      a.p[2] = {xn, WvT[l], nullptr, nullptr, nullptr, vx, nullptr, nullptr};
      a.p[3] = {xn, WqT[l], nullptr, nullptr, nullptr, qy, nullptr, nullptr};
      a.p[4] = {yn, WkT[l], nullptr, nullptr, nullptr, ky, nullptr, nullptr};
      a.p[5] = {yn, WvT[l], nullptr, nullptr, nullptr, vy, nullptr, nullptr};
      gemmf_k<<<dim3(1, BT / 32, 6), 256, 0, stream>>>(a);
    }
    // fused attention
    attn_k<<<dim3(TT / 64, BB * HH), 256, 0, stream>>>(qx, kx, vx, qy, ky, vy, ob1, ob2);
    // output proj + residual + LN2 -> X (fp32) and xn (bf16)
    {
      const float* resx = (l == 0) ? x_in : X;
      const float* resy = (l == 0) ? y_in : Y;
      GemmArgs a = {}; a.K = DDIM; a.N = DDIM; a.gelu = 0; a.ln = 1;
      a.p[0] = {ob1, WoxT[l], box + bo, resx, X, xn, ln2xg + bo, ln2xb + bo};
      a.p[1] = {ob2, WoyT[l], boy + bo, resy, Y, yn, ln2yg + bo, ln2yb + bo};
      gemmf_k<<<dim3(1, BT / 32, 2), 256, 0, stream>>>(a);
    }
    // FFN1 + gelu (bf16 out)
    {
      GemmArgs a = {}; a.K = DDIM; a.N = FF; a.gelu = 1; a.ln = 0;
      a.p[0] = {xn, f1xT[l], fxb1 + fbo, nullptr, nullptr, hx, nullptr, nullptr};
      a.p[1] = {yn, f1yT[l], fyb1 + fbo, nullptr, nullptr, hy, nullptr, nullptr};
      gemmf_k<<<dim3(2, BT / 32, 2), 256, 0, stream>>>(a);
    }
    // FFN2 + residual -> X; layer 0 also fuses next layer's LN1 -> xn
    {
      GemmArgs a = {}; a.K = FF; a.N = DDIM; a.gelu = 0; a.ln = (l == 0) ? 1 : 0;
      if (l == 0) {
        a.p[0] = {hx, f2xT[l], fxb2 + bo, X, X, xn, ln1xg + DDIM, ln1xb + DDIM};
        a.p[1] = {hy, f2yT[l], fyb2 + bo, Y, Y, yn, ln1yg + DDIM, ln1yb + DDIM};
      } else {
        a.p[0] = {hx, f2xT[l], fxb2 + bo, X, X, nullptr, nullptr, nullptr};
        a.p[1] = {hy, f2yT[l], fyb2 + bo, Y, Y, nullptr, nullptr, nullptr};
      }
      gemmf_k<<<dim3(1, BT / 32, 2), 256, 0, stream>>>(a);
    }
  }
}